// Round 8
// baseline (170.791 us; speedup 1.0000x reference)
//
#include <hip/hip_runtime.h>

#define NH 8
#define DCM 64
#define NB 2
#define NS 512
#define NL 384
#define LN_EPS 1e-5f
#define INV_SQRT_C 0.35355339059327379f

typedef __attribute__((ext_vector_type(8))) short short8v;   // 8 bf16 (4 VGPRs)
typedef __attribute__((ext_vector_type(4))) float f32x4;

__device__ __forceinline__ float4 ld4(const float* p) {
  return *reinterpret_cast<const float4*>(p);
}
__device__ __forceinline__ unsigned short f2bf(float f) {
  unsigned int b = __float_as_uint(f);
  b += 0x7FFFu + ((b >> 16) & 1u);          // round-to-nearest-even
  return (unsigned short)(b >> 16);
}
__device__ __forceinline__ float bf2f(unsigned short u) {
  return __uint_as_float(((unsigned int)u) << 16);
}

// ---------------------------------------------------------------------------
// Prep (one-time):
//   wt[0..4095]=wg^T bf16 [n][k]; wt[4096..8191]=wo^T; wt[8192..12287]=wv^T
//   Mg[j*512 + h*64 + cm] = sum_c wq[j][h*8+c]*wk[cm][h*8+c] / sqrt(C)  (f32)
// ---------------------------------------------------------------------------
__global__ void prep(const float* __restrict__ wg, const float* __restrict__ wo,
                     const float* __restrict__ wv, const float* __restrict__ wq,
                     const float* __restrict__ wk,
                     unsigned short* __restrict__ wt, float* __restrict__ Mg) {
  int i = blockIdx.x * 256 + threadIdx.x;
  if (i < 4096) {
    int n = i >> 6, k = i & 63;
    wt[i]        = f2bf(wg[k * DCM + n]);
    wt[4096 + i] = f2bf(wo[k * DCM + n]);
    wt[8192 + i] = f2bf(wv[k * DCM + n]);
  }
  if (i < 32768) {
    int j = i >> 9, idx = i & 511, h = idx >> 6, cm = idx & 63;
    float a = 0.f;
#pragma unroll
    for (int c = 0; c < 8; ++c) a += wq[j * DCM + h * 8 + c] * wk[cm * DCM + h * 8 + c];
    Mg[i] = a * INV_SQRT_C;
  }
}

// ---------------------------------------------------------------------------
// Fused, 256 threads (4 waves), one WG per (b,l) column. m read ONCE.
// x lives ENTIRELY in registers as MFMA A-fragments (xa0/xa1[8], 64 VGPRs):
// lane(bcol,kg) holds rows {wave*128 + t*16 + bcol}, k = kg*8..+7 / 32+kg*8..+7.
//   P1 : LN in fragment layout (2 shuffles/row) + masked q-sum from regs
//   qk : GEMV vs precomputed Mg
//   P2 : logits MFMA -> p (P_T, in-wave) ; V MFMA ; og += p*V
//   P3 : gating MFMA -> transpose via LDS scratch -> output MFMA -> out
// LDS ~12.5 KB; __launch_bounds__(256,3) -> 170-VGPR cap -> 3 waves/SIMD,
// 12 waves/CU, grid 768 = 256 CU x 3 resident.
// ---------------------------------------------------------------------------
__global__ __launch_bounds__(256, 3) void fused(
    const float* __restrict__ m, const float* __restrict__ msk,
    const float* __restrict__ lnw, const float* __restrict__ lnb,
    const unsigned short* __restrict__ wt, const float* __restrict__ Mg,
    const float* __restrict__ bg, const float* __restrict__ bo,
    float* __restrict__ out)
{
  const int col = blockIdx.x;              // b*NL + l
  const int b = col / NL, l = col % NL;
  const int tid = threadIdx.x;
  const int wave = tid >> 6, lane = tid & 63;   // wave 0..3
  const int bcol = lane & 15;              // A-row within 16-tile / B-col
  const int kg = lane >> 4;                // k-group 0..3

  __shared__ __align__(16) unsigned short mask_s[NS];        // 1 KB (0/1 exact)
  __shared__ __align__(16) unsigned char scratch[8192];      // redf / P_T / a2t
  __shared__ __align__(16) unsigned short qk_bf[16 * DCM];   // 2 KB, rows 8-15=0
  __shared__ __align__(16) float ogredf[4 * DCM];            // 1 KB
  __shared__ float smredf[4 * NH];
  __shared__ float ogsf[DCM];
  __shared__ float dredf[4];

  float* redf = (float*)scratch;                    // [4][64] (pre-qk)
  unsigned short* P_T = (unsigned short*)scratch;   // [8][512] bf16 (P2)
  unsigned short* a2t = (unsigned short*)scratch;   // [4][16*64] (P3)

  for (int i = tid; i < NS; i += 256)
    mask_s[i] = f2bf(msk[(b * NS + i) * NL + l]);

  // per-lane LN params for its 16 channels: j<8 -> kg*8+j ; j>=8 -> 32+kg*8+(j-8)
  float lwv[16], lbv[16];
#pragma unroll
  for (int j = 0; j < 8; ++j) {
    lwv[j] = lnw[kg * 8 + j];          lbv[j] = lnb[kg * 8 + j];
    lwv[8 + j] = lnw[32 + kg * 8 + j]; lbv[8 + j] = lnb[32 + kg * 8 + j];
  }
  __syncthreads();                  // mask_s ready

  // ---------------- Phase 1: LN in fragment layout, x -> registers ---------
  const int rowbase = wave * 128;
  short8v xa0[8], xa1[8];
  float qacc[16];
#pragma unroll
  for (int j = 0; j < 16; ++j) qacc[j] = 0.f;
  float dacc = 0.f;
#pragma unroll
  for (int t = 0; t < 8; ++t) {
    const int r = rowbase + t * 16 + bcol;
    const float* rp = m + ((size_t)(b * NS + r) * NL + l) * DCM + kg * 8;
    float4 g0 = ld4(rp);
    float4 g1 = ld4(rp + 4);
    float4 g2 = ld4(rp + 32);
    float4 g3 = ld4(rp + 36);
    const float v[16] = {g0.x,g0.y,g0.z,g0.w, g1.x,g1.y,g1.z,g1.w,
                         g2.x,g2.y,g2.z,g2.w, g3.x,g3.y,g3.z,g3.w};
    float s1 = 0.f, s2 = 0.f;
#pragma unroll
    for (int j = 0; j < 16; ++j) { s1 += v[j]; s2 = fmaf(v[j], v[j], s2); }
    // row r is held by the 4 kg-groups (lane bits 4-5): 2 shuffles complete it
    s1 += __shfl_xor(s1, 16); s1 += __shfl_xor(s1, 32);
    s2 += __shfl_xor(s2, 16); s2 += __shfl_xor(s2, 32);
    const float mu = s1 * 0.015625f;
    const float rs = rsqrtf(s2 * 0.015625f - mu * mu + LN_EPS);
    const float mk = bf2f(mask_s[r]);
    short8v p0, p1;
#pragma unroll
    for (int j = 0; j < 8; ++j) {
      float xn = (v[j] - mu) * rs * lwv[j] + lbv[j];
      p0[j] = (short)f2bf(xn);
      qacc[j] = fmaf(xn, mk, qacc[j]);
      float xn2 = (v[8 + j] - mu) * rs * lwv[8 + j] + lbv[8 + j];
      p1[j] = (short)f2bf(xn2);
      qacc[8 + j] = fmaf(xn2, mk, qacc[8 + j]);
    }
    xa0[t] = p0; xa1[t] = p1;
    dacc += mk;
  }
  // reduce masked sums over bcol (lane bits 0-3): 128 distinct rows, each once;
  // kg replicas hold disjoint channel sets so they stay separate.
#pragma unroll
  for (int o = 1; o <= 8; o <<= 1) {
#pragma unroll
    for (int j = 0; j < 16; ++j) qacc[j] += __shfl_xor(qacc[j], o);
    dacc += __shfl_xor(dacc, o);
  }
  if (bcol == 0) {
#pragma unroll
    for (int j = 0; j < 8; ++j) {
      redf[wave * DCM + kg * 8 + j]      = qacc[j];
      redf[wave * DCM + 32 + kg * 8 + j] = qacc[8 + j];
    }
  }
  if (lane == 0) dredf[wave] = dacc;
  __syncthreads();

  // ---------------- qk GEMV via precomputed Mg -----------------------------
  {
    const float inv_dn = 1.0f / fmaxf((dredf[0] + dredf[1]) + (dredf[2] + dredf[3]), 1.0f);
    float a0 = 0.f, a1 = 0.f;
    for (int j = 0; j < 64; ++j) {
      const float qs = (redf[j] + redf[64 + j]) + (redf[128 + j] + redf[192 + j]);
      a0 = fmaf(qs, Mg[j * 512 + tid], a0);
      a1 = fmaf(qs, Mg[j * 512 + tid + 256], a1);
    }
    qk_bf[tid]       = f2bf(a0 * inv_dn);
    qk_bf[tid + 256] = f2bf(a1 * inv_dn);
    qk_bf[tid + 512] = 0;              // fake heads 8..15 -> zero logits
    qk_bf[tid + 768] = 0;
  }
  __syncthreads();   // qk ready; redf dead -> scratch becomes P_T

  // ---------------- Phase 2 (merged): logits+p, V, og += p*V ---------------
  short8v qkB0 = *reinterpret_cast<const short8v*>(&qk_bf[bcol * DCM + kg * 8]);
  short8v qkB1 = *reinterpret_cast<const short8v*>(&qk_bf[bcol * DCM + 32 + kg * 8]);
  short8v wvB[4][2];
#pragma unroll
  for (int nt = 0; nt < 4; ++nt)
#pragma unroll
    for (int kw = 0; kw < 2; ++kw)
      wvB[nt][kw] = *reinterpret_cast<const short8v*>(
          &wt[8192 + (nt * 16 + bcol) * DCM + kw * 32 + kg * 8]);
  float smacc = 0.f;
  float ogacc[4] = {0.f, 0.f, 0.f, 0.f};
#pragma unroll
  for (int t = 0; t < 8; ++t) {
    f32x4 L = (f32x4){0.f, 0.f, 0.f, 0.f};
    L = __builtin_amdgcn_mfma_f32_16x16x32_bf16(xa0[t], qkB0, L, 0, 0, 0);
    L = __builtin_amdgcn_mfma_f32_16x16x32_bf16(xa1[t], qkB1, L, 0, 0, 0);
    const int s0 = rowbase + t * 16 + kg * 4;        // C rows = kg*4+r
    short4 mk4 = *reinterpret_cast<const short4*>(&mask_s[s0]);
    // logits are tiny (global query is a mean) -> exp without max-sub safe
    float p0 = bf2f((unsigned short)mk4.x) * __expf(L[0]);
    float p1 = bf2f((unsigned short)mk4.y) * __expf(L[1]);
    float p2 = bf2f((unsigned short)mk4.z) * __expf(L[2]);
    float p3 = bf2f((unsigned short)mk4.w) * __expf(L[3]);
    smacc += (p0 + p1) + (p2 + p3);
    if (bcol < NH) {                                 // producer lanes
      short4 pw;
      pw.x = (short)f2bf(p0); pw.y = (short)f2bf(p1);
      pw.z = (short)f2bf(p2); pw.w = (short)f2bf(p3);
      *reinterpret_cast<short4*>(&P_T[bcol * NS + (s0 ^ (bcol << 3))]) = pw;
    }
    f32x4 V[4];
#pragma unroll
    for (int nt = 0; nt < 4; ++nt) {
      V[nt] = (f32x4){0.f, 0.f, 0.f, 0.f};
      V[nt] = __builtin_amdgcn_mfma_f32_16x16x32_bf16(xa0[t], wvB[nt][0], V[nt], 0, 0, 0);
      V[nt] = __builtin_amdgcn_mfma_f32_16x16x32_bf16(xa1[t], wvB[nt][1], V[nt], 0, 0, 0);
    }
    // consume p (stored above by this same wave; in-wave LDS ops are ordered)
#pragma unroll
    for (int nt = 0; nt < 4; ++nt) {
      const int h2 = 2 * nt + (bcol >> 3);           // head of this lane's col
      short4 p4 = *reinterpret_cast<const short4*>(&P_T[h2 * NS + (s0 ^ (h2 << 3))]);
      ogacc[nt] += bf2f((unsigned short)p4.x) * V[nt][0]
                 + bf2f((unsigned short)p4.y) * V[nt][1]
                 + bf2f((unsigned short)p4.z) * V[nt][2]
                 + bf2f((unsigned short)p4.w) * V[nt][3];
    }
  }
  smacc += __shfl_xor(smacc, 16); smacc += __shfl_xor(smacc, 32);
  if (lane < NH) smredf[wave * NH + lane] = smacc;
#pragma unroll
  for (int nt = 0; nt < 4; ++nt) {
    ogacc[nt] += __shfl_xor(ogacc[nt], 16);
    ogacc[nt] += __shfl_xor(ogacc[nt], 32);
  }
  if (lane < 16) {
#pragma unroll
    for (int nt = 0; nt < 4; ++nt) ogredf[wave * DCM + nt * 16 + lane] = ogacc[nt];
  }
  __syncthreads();
  if (tid < DCM) {
    float smT = 0.f, a = 0.f;
#pragma unroll
    for (int w = 0; w < 4; ++w) {
      smT += smredf[w * NH + (tid >> 3)];
      a += ogredf[w * DCM + tid];
    }
    ogsf[tid] = a / fmaxf(smT, 1e-30f);
  }
  __syncthreads();   // og ready; P_T dead -> scratch becomes a2t

  // ---------------- Phase 3: gating MFMA -> LDS transpose -> out MFMA ------
  short8v wgB[4][2], woB[4][2];
  float bgv[4], bov[4], ogv[4];
#pragma unroll
  for (int nt = 0; nt < 4; ++nt) {
    const int ncol = nt * 16 + bcol;
#pragma unroll
    for (int kw = 0; kw < 2; ++kw) {
      wgB[nt][kw] = *reinterpret_cast<const short8v*>(&wt[ncol * DCM + kw * 32 + kg * 8]);
      woB[nt][kw] = *reinterpret_cast<const short8v*>(&wt[4096 + ncol * DCM + kw * 32 + kg * 8]);
    }
    bgv[nt] = bg[ncol]; bov[nt] = bo[ncol]; ogv[nt] = ogsf[ncol];
  }
  const size_t outbase = ((size_t)b * NS * NL + l) * DCM;
  unsigned short* a2w = &a2t[wave * 16 * DCM];       // 2 KB per wave

#pragma unroll
  for (int t = 0; t < 8; ++t) {
    const int tilebase = rowbase + t * 16;
    f32x4 accG[4];
#pragma unroll
    for (int nt = 0; nt < 4; ++nt) {
      accG[nt] = (f32x4){0.f, 0.f, 0.f, 0.f};
      accG[nt] = __builtin_amdgcn_mfma_f32_16x16x32_bf16(xa0[t], wgB[nt][0], accG[nt], 0, 0, 0);
      accG[nt] = __builtin_amdgcn_mfma_f32_16x16x32_bf16(xa1[t], wgB[nt][1], accG[nt], 0, 0, 0);
    }
    // gate*og, transposed bf16 into this wave's scratch (in-wave ordering)
#pragma unroll
    for (int nt = 0; nt < 4; ++nt) {
      const int cc = nt * 16 + bcol;
#pragma unroll
      for (int r = 0; r < 4; ++r) {
        const int r2 = kg * 4 + r;                 // C-layout row within tile
        float gx = accG[nt][r] + bgv[nt];
        float g = 1.0f / (1.0f + __expf(-gx));
        a2w[r2 * DCM + (cc ^ ((r2 & 7) << 3))] = f2bf(g * ogv[nt]);
      }
    }
    short8v b0 = *reinterpret_cast<const short8v*>(
        &a2w[bcol * DCM + ((kg * 8) ^ ((bcol & 7) << 3))]);
    short8v b1 = *reinterpret_cast<const short8v*>(
        &a2w[bcol * DCM + ((32 + kg * 8) ^ ((bcol & 7) << 3))]);
    f32x4 accO[4];
#pragma unroll
    for (int nt = 0; nt < 4; ++nt) {
      accO[nt] = (f32x4){0.f, 0.f, 0.f, 0.f};
      accO[nt] = __builtin_amdgcn_mfma_f32_16x16x32_bf16(b0, woB[nt][0], accO[nt], 0, 0, 0);
      accO[nt] = __builtin_amdgcn_mfma_f32_16x16x32_bf16(b1, woB[nt][1], accO[nt], 0, 0, 0);
    }
#pragma unroll
    for (int nt = 0; nt < 4; ++nt) {
#pragma unroll
      for (int r = 0; r < 4; ++r) {
        const int orow = tilebase + kg * 4 + r;
        const float mk = bf2f(mask_s[orow]);
        out[outbase + (size_t)orow * NL * DCM + nt * 16 + bcol] = (accO[nt][r] + bov[nt]) * mk;
      }
    }
  }
}

extern "C" void kernel_launch(void* const* d_in, const int* in_sizes, int n_in,
                              void* d_out, int out_size, void* d_ws, size_t ws_size,
                              hipStream_t stream) {
  (void)in_sizes; (void)n_in; (void)out_size; (void)ws_size;
  const float* m   = (const float*)d_in[0];
  const float* msk = (const float*)d_in[1];
  const float* lnw = (const float*)d_in[2];
  const float* lnb = (const float*)d_in[3];
  const float* wq  = (const float*)d_in[4];
  const float* wk  = (const float*)d_in[5];
  const float* wv  = (const float*)d_in[6];
  const float* wg  = (const float*)d_in[7];
  const float* bg  = (const float*)d_in[8];
  const float* wo  = (const float*)d_in[9];
  const float* bo  = (const float*)d_in[10];
  unsigned short* wt = (unsigned short*)d_ws;              // 24576 B
  float* Mg = (float*)((char*)d_ws + 24576);               // 131072 B
  float* out = (float*)d_out;

  prep<<<dim3(128), dim3(256), 0, stream>>>(wg, wo, wv, wq, wk, wt, Mg);
  fused<<<dim3(NB * NL), dim3(256), 0, stream>>>(
      m, msk, lnw, lnb, wt, Mg, bg, bo, out);
}

// Round 9
// 92.314 us; speedup vs baseline: 1.8501x; 1.8501x over previous
//
#include <hip/hip_runtime.h>

#define NH 8
#define DCM 64
#define NB 2
#define NS 512
#define NL 384
#define LN_EPS 1e-5f
#define INV_SQRT_C 0.35355339059327379f
#define RSTRIDE (NL * DCM)            // floats between consecutive s rows

typedef __attribute__((ext_vector_type(8))) short short8v;   // 8 bf16 (4 VGPRs)
typedef __attribute__((ext_vector_type(4))) float f32x4;

__device__ __forceinline__ float4 ld4(const float* p) {
  return *reinterpret_cast<const float4*>(p);
}
__device__ __forceinline__ unsigned short f2bf(float f) {
  unsigned int b = __float_as_uint(f);
  b += 0x7FFFu + ((b >> 16) & 1u);          // round-to-nearest-even
  return (unsigned short)(b >> 16);
}
__device__ __forceinline__ float bf2f(unsigned short u) {
  return __uint_as_float(((unsigned int)u) << 16);
}

// ---------------------------------------------------------------------------
// Prep (one-time):
//   wt[0..4095]=wg^T bf16 [n][k]; wt[4096..8191]=wo^T; wt[8192..12287]=wv^T
//   Mg[j*512 + h*64 + cm] = sum_c wq[j][h*8+c]*wk[cm][h*8+c] / sqrt(C)  (f32)
// ---------------------------------------------------------------------------
__global__ void prep(const float* __restrict__ wg, const float* __restrict__ wo,
                     const float* __restrict__ wv, const float* __restrict__ wq,
                     const float* __restrict__ wk,
                     unsigned short* __restrict__ wt, float* __restrict__ Mg) {
  int i = blockIdx.x * 256 + threadIdx.x;
  if (i < 4096) {
    int n = i >> 6, k = i & 63;
    wt[i]        = f2bf(wg[k * DCM + n]);
    wt[4096 + i] = f2bf(wo[k * DCM + n]);
    wt[8192 + i] = f2bf(wv[k * DCM + n]);
  }
  if (i < 32768) {
    int j = i >> 9, idx = i & 511, h = idx >> 6, cm = idx & 63;
    float a = 0.f;
#pragma unroll
    for (int c = 0; c < 8; ++c) a += wq[j * DCM + h * 8 + c] * wk[cm * DCM + h * 8 + c];
    Mg[i] = a * INV_SQRT_C;
  }
}

// ---------------------------------------------------------------------------
// Fused, 256 threads (4 waves), one WG per (b,l) column. NO persistent x:
// each phase re-reads its 16-row m tile (L3-resident) and re-applies LN via a
// per-row (mu,rs) LDS table (4 KB). LDS ~17 KB -> grid-bound occupancy:
// 3 WG/CU resident (768 WGs / 256 CUs), 12 waves/CU — 1.5x R4.
//   P2a: stats pass  — per-row mu/rs -> murs; masked q-sum -> redf
//   qk : GEMV vs precomputed Mg (folds q_input->q->qk)
//   P2b: attention   — reload tile, logits MFMA -> p (P_T, in-wave),
//                      V MFMA, og += p*V
//   P3 : output      — reload tile, gating MFMA -> LDS transpose -> out MFMA
// Plain __launch_bounds__(256): arg2 variants caused spills (R5/R8) or were
// ignored (R7); compiler naturally picks ~112 VGPR on this code shape (R4).
// ---------------------------------------------------------------------------
__global__ __launch_bounds__(256) void fused(
    const float* __restrict__ m, const float* __restrict__ msk,
    const float* __restrict__ lnw, const float* __restrict__ lnb,
    const unsigned short* __restrict__ wt, const float* __restrict__ Mg,
    const float* __restrict__ bg, const float* __restrict__ bo,
    float* __restrict__ out)
{
  const int col = blockIdx.x;              // b*NL + l
  const int b = col / NL, l = col % NL;
  const int tid = threadIdx.x;
  const int wave = tid >> 6, lane = tid & 63;   // wave 0..3
  const int bcol = lane & 15;              // A-row within 16-tile / B-col
  const int kg = lane >> 4;                // k-group 0..3

  __shared__ __align__(16) unsigned short mask_s[NS];        // 1 KB (0/1 exact)
  __shared__ __align__(16) float murs[NS * 2];               // 4 KB (mu,rs)/row
  __shared__ __align__(16) unsigned char scratch[8192];      // redf / P_T / a2t
  __shared__ __align__(16) unsigned short qk_bf[16 * DCM];   // 2 KB, rows 8-15=0
  __shared__ __align__(16) float ogredf[4 * DCM];            // 1 KB
  __shared__ float smredf[4 * NH];
  __shared__ float ogsf[DCM];
  __shared__ float dredf[4];

  float* redf = (float*)scratch;                    // [4][64] (pre-qk)
  unsigned short* P_T = (unsigned short*)scratch;   // [8][512] bf16 (P2b)
  unsigned short* a2t = (unsigned short*)scratch;   // [4][16*64] (P3)

  for (int i = tid; i < NS; i += 256)
    mask_s[i] = f2bf(msk[(b * NS + i) * NL + l]);

  // per-lane LN params for its 16 channels: j<8 -> kg*8+j ; j>=8 -> 32+kg*8+j
  float lwv[16], lbv[16];
#pragma unroll
  for (int j = 0; j < 8; ++j) {
    lwv[j] = lnw[kg * 8 + j];          lbv[j] = lnb[kg * 8 + j];
    lwv[8 + j] = lnw[32 + kg * 8 + j]; lbv[8 + j] = lnb[32 + kg * 8 + j];
  }
  const float* mbase = m + ((size_t)b * NS * NL + l) * DCM + kg * 8;
  const int rowbase = wave * 128;
  __syncthreads();                  // mask_s ready

  // ---------------- P2a: stats pass (mu/rs -> LDS, masked q-sum) -----------
  float qacc[16];
#pragma unroll
  for (int j = 0; j < 16; ++j) qacc[j] = 0.f;
  float dacc = 0.f;
#pragma unroll 4
  for (int t = 0; t < 8; ++t) {
    const int r = rowbase + t * 16 + bcol;
    const float* rp = mbase + (size_t)r * RSTRIDE;
    float4 g0 = ld4(rp), g1 = ld4(rp + 4), g2 = ld4(rp + 32), g3 = ld4(rp + 36);
    const float v[16] = {g0.x,g0.y,g0.z,g0.w, g1.x,g1.y,g1.z,g1.w,
                         g2.x,g2.y,g2.z,g2.w, g3.x,g3.y,g3.z,g3.w};
    float s1 = 0.f, s2 = 0.f;
#pragma unroll
    for (int j = 0; j < 16; ++j) { s1 += v[j]; s2 = fmaf(v[j], v[j], s2); }
    // row r is spread over the 4 kg-groups (lane bits 4-5): 2 shuffles
    s1 += __shfl_xor(s1, 16); s1 += __shfl_xor(s1, 32);
    s2 += __shfl_xor(s2, 16); s2 += __shfl_xor(s2, 32);
    const float mu = s1 * 0.015625f;
    const float rs = rsqrtf(s2 * 0.015625f - mu * mu + LN_EPS);
    if (kg == 0) { murs[2 * r] = mu; murs[2 * r + 1] = rs; }
    const float mk = bf2f(mask_s[r]);
#pragma unroll
    for (int j = 0; j < 16; ++j)
      qacc[j] = fmaf((v[j] - mu) * rs * lwv[j] + lbv[j], mk, qacc[j]);
    dacc += mk;
  }
  // reduce over bcol (lane bits 0-3): 128 distinct rows each counted once;
  // kg replicas hold disjoint channel sets and stay separate.
#pragma unroll
  for (int o = 1; o <= 8; o <<= 1) {
#pragma unroll
    for (int j = 0; j < 16; ++j) qacc[j] += __shfl_xor(qacc[j], o);
    dacc += __shfl_xor(dacc, o);
  }
  if (bcol == 0) {
#pragma unroll
    for (int j = 0; j < 8; ++j) {
      redf[wave * DCM + kg * 8 + j]      = qacc[j];
      redf[wave * DCM + 32 + kg * 8 + j] = qacc[8 + j];
    }
  }
  if (lane == 0) dredf[wave] = dacc;
  __syncthreads();

  // ---------------- qk GEMV via precomputed Mg -----------------------------
  {
    const float inv_dn = 1.0f / fmaxf((dredf[0] + dredf[1]) + (dredf[2] + dredf[3]), 1.0f);
    float a0 = 0.f, a1 = 0.f;
    for (int j = 0; j < 64; ++j) {
      const float qs = (redf[j] + redf[64 + j]) + (redf[128 + j] + redf[192 + j]);
      a0 = fmaf(qs, Mg[j * 512 + tid], a0);
      a1 = fmaf(qs, Mg[j * 512 + tid + 256], a1);
    }
    qk_bf[tid]       = f2bf(a0 * inv_dn);
    qk_bf[tid + 256] = f2bf(a1 * inv_dn);
    qk_bf[tid + 512] = 0;              // fake heads 8..15 -> zero logits
    qk_bf[tid + 768] = 0;
  }
  __syncthreads();   // qk ready; redf dead -> scratch becomes P_T

  // ---------------- P2b: attention pass (reload + re-LN per tile) ----------
  short8v qkB0 = *reinterpret_cast<const short8v*>(&qk_bf[bcol * DCM + kg * 8]);
  short8v qkB1 = *reinterpret_cast<const short8v*>(&qk_bf[bcol * DCM + 32 + kg * 8]);
  short8v wvB[4][2];
#pragma unroll
  for (int nt = 0; nt < 4; ++nt)
#pragma unroll
    for (int kw = 0; kw < 2; ++kw)
      wvB[nt][kw] = *reinterpret_cast<const short8v*>(
          &wt[8192 + (nt * 16 + bcol) * DCM + kw * 32 + kg * 8]);
  float smacc = 0.f;
  float ogacc[4] = {0.f, 0.f, 0.f, 0.f};
#pragma unroll 2
  for (int t = 0; t < 8; ++t) {
    const int r = rowbase + t * 16 + bcol;
    const float* rp = mbase + (size_t)r * RSTRIDE;
    float4 g0 = ld4(rp), g1 = ld4(rp + 4), g2 = ld4(rp + 32), g3 = ld4(rp + 36);
    const float v[16] = {g0.x,g0.y,g0.z,g0.w, g1.x,g1.y,g1.z,g1.w,
                         g2.x,g2.y,g2.z,g2.w, g3.x,g3.y,g3.z,g3.w};
    const float mu = murs[2 * r], rs = murs[2 * r + 1];
    short8v xa0, xa1;
#pragma unroll
    for (int j = 0; j < 8; ++j) {
      xa0[j] = (short)f2bf((v[j] - mu) * rs * lwv[j] + lbv[j]);
      xa1[j] = (short)f2bf((v[8 + j] - mu) * rs * lwv[8 + j] + lbv[8 + j]);
    }
    f32x4 L = (f32x4){0.f, 0.f, 0.f, 0.f};
    L = __builtin_amdgcn_mfma_f32_16x16x32_bf16(xa0, qkB0, L, 0, 0, 0);
    L = __builtin_amdgcn_mfma_f32_16x16x32_bf16(xa1, qkB1, L, 0, 0, 0);
    const int s0 = rowbase + t * 16 + kg * 4;        // C rows = kg*4+r
    short4 mk4 = *reinterpret_cast<const short4*>(&mask_s[s0]);
    // logits are tiny (global query is a mean) -> exp without max-sub safe
    float p0 = bf2f((unsigned short)mk4.x) * __expf(L[0]);
    float p1 = bf2f((unsigned short)mk4.y) * __expf(L[1]);
    float p2 = bf2f((unsigned short)mk4.z) * __expf(L[2]);
    float p3 = bf2f((unsigned short)mk4.w) * __expf(L[3]);
    smacc += (p0 + p1) + (p2 + p3);
    if (bcol < NH) {                                 // producer lanes
      short4 pw;
      pw.x = (short)f2bf(p0); pw.y = (short)f2bf(p1);
      pw.z = (short)f2bf(p2); pw.w = (short)f2bf(p3);
      *reinterpret_cast<short4*>(&P_T[bcol * NS + (s0 ^ (bcol << 3))]) = pw;
    }
    f32x4 V[4];
#pragma unroll
    for (int nt = 0; nt < 4; ++nt) {
      V[nt] = (f32x4){0.f, 0.f, 0.f, 0.f};
      V[nt] = __builtin_amdgcn_mfma_f32_16x16x32_bf16(xa0, wvB[nt][0], V[nt], 0, 0, 0);
      V[nt] = __builtin_amdgcn_mfma_f32_16x16x32_bf16(xa1, wvB[nt][1], V[nt], 0, 0, 0);
    }
    // consume p (stored above by this same wave; in-wave LDS ops are ordered)
#pragma unroll
    for (int nt = 0; nt < 4; ++nt) {
      const int h2 = 2 * nt + (bcol >> 3);           // head of this lane's col
      short4 p4 = *reinterpret_cast<const short4*>(&P_T[h2 * NS + (s0 ^ (h2 << 3))]);
      ogacc[nt] += bf2f((unsigned short)p4.x) * V[nt][0]
                 + bf2f((unsigned short)p4.y) * V[nt][1]
                 + bf2f((unsigned short)p4.z) * V[nt][2]
                 + bf2f((unsigned short)p4.w) * V[nt][3];
    }
  }
  smacc += __shfl_xor(smacc, 16); smacc += __shfl_xor(smacc, 32);
  if (lane < NH) smredf[wave * NH + lane] = smacc;
#pragma unroll
  for (int nt = 0; nt < 4; ++nt) {
    ogacc[nt] += __shfl_xor(ogacc[nt], 16);
    ogacc[nt] += __shfl_xor(ogacc[nt], 32);
  }
  if (lane < 16) {
#pragma unroll
    for (int nt = 0; nt < 4; ++nt) ogredf[wave * DCM + nt * 16 + lane] = ogacc[nt];
  }
  __syncthreads();
  if (tid < DCM) {
    float smT = 0.f, a = 0.f;
#pragma unroll
    for (int w = 0; w < 4; ++w) {
      smT += smredf[w * NH + (tid >> 3)];
      a += ogredf[w * DCM + tid];
    }
    ogsf[tid] = a / fmaxf(smT, 1e-30f);
  }
  __syncthreads();   // og ready; P_T dead -> scratch becomes a2t

  // ---------------- P3: output pass (reload + re-LN per tile) --------------
  short8v wgB[4][2], woB[4][2];
  float bgv[4], bov[4], ogv[4];
#pragma unroll
  for (int nt = 0; nt < 4; ++nt) {
    const int ncol = nt * 16 + bcol;
#pragma unroll
    for (int kw = 0; kw < 2; ++kw) {
      wgB[nt][kw] = *reinterpret_cast<const short8v*>(&wt[ncol * DCM + kw * 32 + kg * 8]);
      woB[nt][kw] = *reinterpret_cast<const short8v*>(&wt[4096 + ncol * DCM + kw * 32 + kg * 8]);
    }
    bgv[nt] = bg[ncol]; bov[nt] = bo[ncol]; ogv[nt] = ogsf[ncol];
  }
  const size_t outbase = ((size_t)b * NS * NL + l) * DCM;
  unsigned short* a2w = &a2t[wave * 16 * DCM];       // 2 KB per wave

#pragma unroll 2
  for (int t = 0; t < 8; ++t) {
    const int tilebase = rowbase + t * 16;
    const int r = tilebase + bcol;
    const float* rp = mbase + (size_t)r * RSTRIDE;
    float4 g0 = ld4(rp), g1 = ld4(rp + 4), g2 = ld4(rp + 32), g3 = ld4(rp + 36);
    const float v[16] = {g0.x,g0.y,g0.z,g0.w, g1.x,g1.y,g1.z,g1.w,
                         g2.x,g2.y,g2.z,g2.w, g3.x,g3.y,g3.z,g3.w};
    const float mu = murs[2 * r], rs = murs[2 * r + 1];
    short8v xa0, xa1;
#pragma unroll
    for (int j = 0; j < 8; ++j) {
      xa0[j] = (short)f2bf((v[j] - mu) * rs * lwv[j] + lbv[j]);
      xa1[j] = (short)f2bf((v[8 + j] - mu) * rs * lwv[8 + j] + lbv[8 + j]);
    }
    f32x4 accG[4];
#pragma unroll
    for (int nt = 0; nt < 4; ++nt) {
      accG[nt] = (f32x4){0.f, 0.f, 0.f, 0.f};
      accG[nt] = __builtin_amdgcn_mfma_f32_16x16x32_bf16(xa0, wgB[nt][0], accG[nt], 0, 0, 0);
      accG[nt] = __builtin_amdgcn_mfma_f32_16x16x32_bf16(xa1, wgB[nt][1], accG[nt], 0, 0, 0);
    }
    // gate*og, transposed bf16 into this wave's scratch (in-wave ordering)
#pragma unroll
    for (int nt = 0; nt < 4; ++nt) {
      const int cc = nt * 16 + bcol;
#pragma unroll
      for (int r2i = 0; r2i < 4; ++r2i) {
        const int r2 = kg * 4 + r2i;               // C-layout row within tile
        float gx = accG[nt][r2i] + bgv[nt];
        float g = 1.0f / (1.0f + __expf(-gx));
        a2w[r2 * DCM + (cc ^ ((r2 & 7) << 3))] = f2bf(g * ogv[nt]);
      }
    }
    short8v b0 = *reinterpret_cast<const short8v*>(
        &a2w[bcol * DCM + ((kg * 8) ^ ((bcol & 7) << 3))]);
    short8v b1 = *reinterpret_cast<const short8v*>(
        &a2w[bcol * DCM + ((32 + kg * 8) ^ ((bcol & 7) << 3))]);
    f32x4 accO[4];
#pragma unroll
    for (int nt = 0; nt < 4; ++nt) {
      accO[nt] = (f32x4){0.f, 0.f, 0.f, 0.f};
      accO[nt] = __builtin_amdgcn_mfma_f32_16x16x32_bf16(b0, woB[nt][0], accO[nt], 0, 0, 0);
      accO[nt] = __builtin_amdgcn_mfma_f32_16x16x32_bf16(b1, woB[nt][1], accO[nt], 0, 0, 0);
    }
#pragma unroll
    for (int nt = 0; nt < 4; ++nt) {
#pragma unroll
      for (int r2i = 0; r2i < 4; ++r2i) {
        const int orow = tilebase + kg * 4 + r2i;
        const float mk = bf2f(mask_s[orow]);
        out[outbase + (size_t)orow * NL * DCM + nt * 16 + bcol] = (accO[nt][r2i] + bov[nt]) * mk;
      }
    }
  }
}

extern "C" void kernel_launch(void* const* d_in, const int* in_sizes, int n_in,
                              void* d_out, int out_size, void* d_ws, size_t ws_size,
                              hipStream_t stream) {
  (void)in_sizes; (void)n_in; (void)out_size; (void)ws_size;
  const float* m   = (const float*)d_in[0];
  const float* msk = (const float*)d_in[1];
  const float* lnw = (const float*)d_in[2];
  const float* lnb = (const float*)d_in[3];
  const float* wq  = (const float*)d_in[4];
  const float* wk  = (const float*)d_in[5];
  const float* wv  = (const float*)d_in[6];
  const float* wg  = (const float*)d_in[7];
  const float* bg  = (const float*)d_in[8];
  const float* wo  = (const float*)d_in[9];
  const float* bo  = (const float*)d_in[10];
  unsigned short* wt = (unsigned short*)d_ws;              // 24576 B
  float* Mg = (float*)((char*)d_ws + 24576);               // 131072 B
  float* out = (float*)d_out;

  prep<<<dim3(128), dim3(256), 0, stream>>>(wg, wo, wv, wq, wk, wt, Mg);
  fused<<<dim3(NB * NL), dim3(256), 0, stream>>>(
      m, msk, lnw, lnb, wt, Mg, bg, bo, out);
}

// Round 11
// 86.277 us; speedup vs baseline: 1.9796x; 1.0700x over previous
//
#include <hip/hip_runtime.h>
#include <hip/hip_bf16.h>

#define NH 8
#define DCM 64
#define NB 2
#define NS 512
#define NL 384
#define LN_EPS 1e-5f
#define INV_SQRT_C 0.35355339059327379f

typedef __attribute__((ext_vector_type(8))) short short8v;   // 8 bf16 (4 VGPRs)
typedef __attribute__((ext_vector_type(4))) float f32x4;

__device__ __forceinline__ float4 ld4(const float* p) {
  return *reinterpret_cast<const float4*>(p);
}
__device__ __forceinline__ unsigned short f2bf(float f) {
  __hip_bfloat16 h = __float2bfloat16(f);       // RNE
  return __builtin_bit_cast(unsigned short, h);
}
__device__ __forceinline__ float bf2f(unsigned short u) {
  return __uint_as_float(((unsigned int)u) << 16);
}

// ---------------------------------------------------------------------------
// Prep (one-time):
//   wt[0..4095]=wg^T bf16 [n][k]; wt[4096..8191]=wo^T; wt[8192..12287]=wv^T
//   Mg[j*512 + h*64 + cm] = sum_c wq[j][h*8+c]*wk[cm][h*8+c] / sqrt(C)  (f32)
// ---------------------------------------------------------------------------
__global__ void prep(const float* __restrict__ wg, const float* __restrict__ wo,
                     const float* __restrict__ wv, const float* __restrict__ wq,
                     const float* __restrict__ wk,
                     unsigned short* __restrict__ wt, float* __restrict__ Mg) {
  int i = blockIdx.x * 256 + threadIdx.x;
  if (i < 4096) {
    int n = i >> 6, k = i & 63;
    wt[i]        = f2bf(wg[k * DCM + n]);
    wt[4096 + i] = f2bf(wo[k * DCM + n]);
    wt[8192 + i] = f2bf(wv[k * DCM + n]);
  }
  if (i < 32768) {
    int j = i >> 9, idx = i & 511, h = idx >> 6, cm = idx & 63;
    float a = 0.f;
#pragma unroll
    for (int c = 0; c < 8; ++c) a += wq[j * DCM + h * 8 + c] * wk[cm * DCM + h * 8 + c];
    Mg[i] = a * INV_SQRT_C;
  }
}

// ---------------------------------------------------------------------------
// Fused, 256 threads (4 waves), one WG per (b,l) column — consolidation of
// ONLY post-timing-proven pieces:
//   P1 : stream m once (depth-4 prefetch), LN, x bf16 -> x_lds (swizzled),
//        masked q-sum -> redf                       [R4/R6 proven]
//   qk : one GEMV vs precomputed Mg                 [R7/R9 proven]
//   P2 : merged: logits MFMA -> p (P_T, in-wave); V MFMA; og += p*V
//                                                   [R6/R7/R9 proven]
//   P3 : gating MFMA -> sigmoid*og -> bf16 transpose via wave-private a2t
//        scratch -> output MFMA -> out              [R7/R9 proven]
// R10's in-place-gx-into-x_lds variant is REVERTED: it was the only new
// LDS-lifetime trick in the only round that failed post-timing revalidation.
// ---------------------------------------------------------------------------
__global__ __launch_bounds__(256) void fused(
    const float* __restrict__ m, const float* __restrict__ msk,
    const float* __restrict__ lnw, const float* __restrict__ lnb,
    const unsigned short* __restrict__ wt, const float* __restrict__ Mg,
    const float* __restrict__ bg, const float* __restrict__ bo,
    float* __restrict__ out)
{
  const int col = blockIdx.x;              // b*NL + l
  const int b = col / NL, l = col % NL;
  const int tid = threadIdx.x;
  const int wave = tid >> 6, lane = tid & 63;   // wave 0..3

  __shared__ __align__(16) unsigned short x_lds[NS * DCM];   // 64 KB, swizzled
  __shared__ __align__(16) unsigned short mask_s[NS];        // 1 KB (0/1 exact)
  __shared__ __align__(16) unsigned char scratch[8192];      // redf / P_T / a2t
  __shared__ __align__(16) unsigned short qk_bf[16 * DCM];   // 2 KB, rows 8-15=0
  __shared__ __align__(16) float ogredf[4 * DCM];            // 1 KB
  __shared__ float smredf[4 * NH];
  __shared__ float ogsf[DCM];
  __shared__ float dredf[4];

  float* redf = (float*)scratch;                    // [4][64] (pre-qk)
  unsigned short* P_T = (unsigned short*)scratch;   // [8][512] bf16 (P2)
  unsigned short* a2t = (unsigned short*)scratch;   // [4][16*64] (P3)

  for (int i = tid; i < NS; i += 256)
    mask_s[i] = f2bf(msk[(b * NS + i) * NL + l]);

  // ---------------- Phase 1: stream m once, LN, x->LDS bf16, masked sum ----
  const int c8 = lane & 7;          // channel block: cm = c8*8 .. c8*8+7
  const int r8 = lane >> 3;         // row within 8-row group
  const float* mbase = m + ((size_t)b * NS * NL + l) * DCM + c8 * 8;
  float lw8[8], lb8[8];
#pragma unroll
  for (int k = 0; k < 8; ++k) { lw8[k] = lnw[c8 * 8 + k]; lb8[k] = lnb[c8 * 8 + k]; }
  __syncthreads();                  // mask_s ready

  float qacc[8] = {0.f,0.f,0.f,0.f,0.f,0.f,0.f,0.f};
  float dacc = 0.f;
  const int rowbase = wave * 128;
  {
    const size_t rstep = (size_t)8 * NL * DCM;
    const float* mb = mbase + (size_t)(rowbase + r8) * NL * DCM;
    auto process = [&](const float4& A, const float4& Bv, int s) {
      float xv[8] = {A.x, A.y, A.z, A.w, Bv.x, Bv.y, Bv.z, Bv.w};
      float s1 = 0.f, s2 = 0.f;
#pragma unroll
      for (int k = 0; k < 8; ++k) { s1 += xv[k]; s2 = fmaf(xv[k], xv[k], s2); }
#pragma unroll
      for (int o = 1; o <= 4; o <<= 1) { s1 += __shfl_xor(s1, o); s2 += __shfl_xor(s2, o); }
      const float mu = s1 * 0.015625f;
      const float rs = rsqrtf(s2 * 0.015625f - mu * mu + LN_EPS);
      const float mk = bf2f(mask_s[s]);
      short8v xp;
#pragma unroll
      for (int k = 0; k < 8; ++k) {
        float xn = (xv[k] - mu) * rs * lw8[k] + lb8[k];
        xp[k] = (short)f2bf(xn);
        qacc[k] = fmaf(xn, mk, qacc[k]);
      }
      dacc += mk;
      *reinterpret_cast<short8v*>(&x_lds[s * DCM + ((c8 * 8) ^ ((s & 7) << 3))]) = xp;
    };
    // depth-4 prefetch, static register indexing
    float4 f0a = ld4(mb),             f0b = ld4(mb + 4);
    float4 f1a = ld4(mb + rstep),     f1b = ld4(mb + rstep + 4);
    float4 f2a = ld4(mb + 2 * rstep), f2b = ld4(mb + 2 * rstep + 4);
    float4 f3a = ld4(mb + 3 * rstep), f3b = ld4(mb + 3 * rstep + 4);
#pragma unroll
    for (int blk = 0; blk < 4; ++blk) {
      const int it0 = blk * 4;
      process(f0a, f0b, rowbase + (it0 + 0) * 8 + r8);
      if (blk < 3) { f0a = ld4(mb + (size_t)(it0 + 4) * rstep);
                     f0b = ld4(mb + (size_t)(it0 + 4) * rstep + 4); }
      process(f1a, f1b, rowbase + (it0 + 1) * 8 + r8);
      if (blk < 3) { f1a = ld4(mb + (size_t)(it0 + 5) * rstep);
                     f1b = ld4(mb + (size_t)(it0 + 5) * rstep + 4); }
      process(f2a, f2b, rowbase + (it0 + 2) * 8 + r8);
      if (blk < 3) { f2a = ld4(mb + (size_t)(it0 + 6) * rstep);
                     f2b = ld4(mb + (size_t)(it0 + 6) * rstep + 4); }
      process(f3a, f3b, rowbase + (it0 + 3) * 8 + r8);
      if (blk < 3) { f3a = ld4(mb + (size_t)(it0 + 7) * rstep);
                     f3b = ld4(mb + (size_t)(it0 + 7) * rstep + 4); }
    }
  }
#pragma unroll
  for (int o = 8; o <= 32; o <<= 1) {
#pragma unroll
    for (int k = 0; k < 8; ++k) qacc[k] += __shfl_xor(qacc[k], o);
    dacc += __shfl_xor(dacc, o);
  }
  if (lane < 8) {
    float4 t0; t0.x = qacc[0]; t0.y = qacc[1]; t0.z = qacc[2]; t0.w = qacc[3];
    float4 t1; t1.x = qacc[4]; t1.y = qacc[5]; t1.z = qacc[6]; t1.w = qacc[7];
    *reinterpret_cast<float4*>(&redf[wave * DCM + lane * 8])     = t0;
    *reinterpret_cast<float4*>(&redf[wave * DCM + lane * 8 + 4]) = t1;
  }
  // xor-reduce over {8,16,32} sums r8 only -> each of the wave's 128 rows
  // counted exactly once (c8 replicas in lane bits 0-2 never merged)
  if (lane == 0) dredf[wave] = dacc;
  __syncthreads();

  // ---------------- qk GEMV via precomputed Mg -----------------------------
  {
    const float inv_dn = 1.0f / fmaxf((dredf[0] + dredf[1]) + (dredf[2] + dredf[3]), 1.0f);
    float a0 = 0.f, a1 = 0.f;
    for (int j = 0; j < 64; ++j) {
      const float qs = (redf[j] + redf[64 + j]) + (redf[128 + j] + redf[192 + j]);
      a0 = fmaf(qs, Mg[j * 512 + tid], a0);
      a1 = fmaf(qs, Mg[j * 512 + tid + 256], a1);
    }
    qk_bf[tid]       = f2bf(a0 * inv_dn);
    qk_bf[tid + 256] = f2bf(a1 * inv_dn);
    qk_bf[tid + 512] = 0;              // fake heads 8..15 -> zero logits
    qk_bf[tid + 768] = 0;
  }
  __syncthreads();   // qk ready; redf dead -> scratch becomes P_T

  // ---------------- Phase 2 (merged): logits+p, V, og += p*V ---------------
  const int bcol = lane & 15;
  const int kg = lane >> 4;
  short8v qkB0 = *reinterpret_cast<const short8v*>(&qk_bf[bcol * DCM + kg * 8]);
  short8v qkB1 = *reinterpret_cast<const short8v*>(&qk_bf[bcol * DCM + 32 + kg * 8]);
  short8v wvB[4][2];
#pragma unroll
  for (int nt = 0; nt < 4; ++nt)
#pragma unroll
    for (int kw = 0; kw < 2; ++kw)
      wvB[nt][kw] = *reinterpret_cast<const short8v*>(
          &wt[8192 + (nt * 16 + bcol) * DCM + kw * 32 + kg * 8]);
  float smacc = 0.f;
  float ogacc[4] = {0.f, 0.f, 0.f, 0.f};
  for (int t = 0; t < 8; ++t) {
    const int tilebase = rowbase + t * 16;
    const int arow = tilebase + bcol;
    const int swz = (arow & 7) << 3;
    short8v a0 = *reinterpret_cast<const short8v*>(&x_lds[arow * DCM + ((kg * 8) ^ swz)]);
    short8v a1 = *reinterpret_cast<const short8v*>(&x_lds[arow * DCM + ((32 + kg * 8) ^ swz)]);
    f32x4 L = (f32x4){0.f, 0.f, 0.f, 0.f};
    L = __builtin_amdgcn_mfma_f32_16x16x32_bf16(a0, qkB0, L, 0, 0, 0);
    L = __builtin_amdgcn_mfma_f32_16x16x32_bf16(a1, qkB1, L, 0, 0, 0);
    const int s0 = tilebase + kg * 4;                // C rows = kg*4+r
    short4 mk4 = *reinterpret_cast<const short4*>(&mask_s[s0]);
    // logits are tiny (global query is a mean) -> exp without max-sub safe
    float p0 = bf2f((unsigned short)mk4.x) * __expf(L[0]);
    float p1 = bf2f((unsigned short)mk4.y) * __expf(L[1]);
    float p2 = bf2f((unsigned short)mk4.z) * __expf(L[2]);
    float p3 = bf2f((unsigned short)mk4.w) * __expf(L[3]);
    smacc += (p0 + p1) + (p2 + p3);
    if (bcol < NH) {                                 // producer lanes
      short4 pw;
      pw.x = (short)f2bf(p0); pw.y = (short)f2bf(p1);
      pw.z = (short)f2bf(p2); pw.w = (short)f2bf(p3);
      *reinterpret_cast<short4*>(&P_T[bcol * NS + (s0 ^ (bcol << 3))]) = pw;
    }
    f32x4 V[4];
#pragma unroll
    for (int nt = 0; nt < 4; ++nt) {
      V[nt] = (f32x4){0.f, 0.f, 0.f, 0.f};
      V[nt] = __builtin_amdgcn_mfma_f32_16x16x32_bf16(a0, wvB[nt][0], V[nt], 0, 0, 0);
      V[nt] = __builtin_amdgcn_mfma_f32_16x16x32_bf16(a1, wvB[nt][1], V[nt], 0, 0, 0);
    }
    // consume p (stored above by this same wave; in-wave LDS ops are ordered)
#pragma unroll
    for (int nt = 0; nt < 4; ++nt) {
      const int h2 = 2 * nt + (bcol >> 3);           // head of this lane's col
      short4 p4 = *reinterpret_cast<const short4*>(&P_T[h2 * NS + (s0 ^ (h2 << 3))]);
      ogacc[nt] += bf2f((unsigned short)p4.x) * V[nt][0]
                 + bf2f((unsigned short)p4.y) * V[nt][1]
                 + bf2f((unsigned short)p4.z) * V[nt][2]
                 + bf2f((unsigned short)p4.w) * V[nt][3];
    }
  }
  smacc += __shfl_xor(smacc, 16); smacc += __shfl_xor(smacc, 32);
  if (lane < NH) smredf[wave * NH + lane] = smacc;
#pragma unroll
  for (int nt = 0; nt < 4; ++nt) {
    ogacc[nt] += __shfl_xor(ogacc[nt], 16);
    ogacc[nt] += __shfl_xor(ogacc[nt], 32);
  }
  if (lane < 16) {
#pragma unroll
    for (int nt = 0; nt < 4; ++nt) ogredf[wave * DCM + nt * 16 + lane] = ogacc[nt];
  }
  __syncthreads();
  if (tid < DCM) {
    float smT = 0.f, a = 0.f;
#pragma unroll
    for (int w = 0; w < 4; ++w) {
      smT += smredf[w * NH + (tid >> 3)];
      a += ogredf[w * DCM + tid];
    }
    ogsf[tid] = a / fmaxf(smT, 1e-30f);
  }
  __syncthreads();   // og ready; P_T dead -> scratch becomes a2t

  // ---------------- Phase 3: gating MFMA -> a2t transpose -> out MFMA ------
  short8v wgB[4][2], woB[4][2];
  float bgv[4], bov[4], ogv[4];
#pragma unroll
  for (int nt = 0; nt < 4; ++nt) {
    const int ncol = nt * 16 + bcol;
#pragma unroll
    for (int kw = 0; kw < 2; ++kw) {
      wgB[nt][kw] = *reinterpret_cast<const short8v*>(&wt[ncol * DCM + kw * 32 + kg * 8]);
      woB[nt][kw] = *reinterpret_cast<const short8v*>(&wt[4096 + ncol * DCM + kw * 32 + kg * 8]);
    }
    bgv[nt] = bg[ncol]; bov[nt] = bo[ncol]; ogv[nt] = ogsf[ncol];
  }
  const size_t outbase = ((size_t)b * NS * NL + l) * DCM;
  unsigned short* a2w = &a2t[wave * 16 * DCM];       // 2 KB per wave

  for (int t = 0; t < 8; ++t) {
    const int tilebase = rowbase + t * 16;
    const int arow = tilebase + bcol;
    const int swz = (arow & 7) << 3;
    short8v a0 = *reinterpret_cast<const short8v*>(&x_lds[arow * DCM + ((kg * 8) ^ swz)]);
    short8v a1 = *reinterpret_cast<const short8v*>(&x_lds[arow * DCM + ((32 + kg * 8) ^ swz)]);
    f32x4 accG[4];
#pragma unroll
    for (int nt = 0; nt < 4; ++nt) {
      accG[nt] = (f32x4){0.f, 0.f, 0.f, 0.f};
      accG[nt] = __builtin_amdgcn_mfma_f32_16x16x32_bf16(a0, wgB[nt][0], accG[nt], 0, 0, 0);
      accG[nt] = __builtin_amdgcn_mfma_f32_16x16x32_bf16(a1, wgB[nt][1], accG[nt], 0, 0, 0);
    }
    // sigmoid gate * og, transposed bf16 into this wave's scratch
#pragma unroll
    for (int nt = 0; nt < 4; ++nt) {
      const int cc = nt * 16 + bcol;
#pragma unroll
      for (int r = 0; r < 4; ++r) {
        const int r2 = kg * 4 + r;                 // C-layout row within tile
        float gx = accG[nt][r] + bgv[nt];
        float g = 1.0f / (1.0f + __expf(-gx));
        a2w[r2 * DCM + (cc ^ ((r2 & 7) << 3))] = f2bf(g * ogv[nt]);
      }
    }
    short8v b0 = *reinterpret_cast<const short8v*>(
        &a2w[bcol * DCM + ((kg * 8) ^ ((bcol & 7) << 3))]);
    short8v b1 = *reinterpret_cast<const short8v*>(
        &a2w[bcol * DCM + ((32 + kg * 8) ^ ((bcol & 7) << 3))]);
    f32x4 accO[4];
#pragma unroll
    for (int nt = 0; nt < 4; ++nt) {
      accO[nt] = (f32x4){0.f, 0.f, 0.f, 0.f};
      accO[nt] = __builtin_amdgcn_mfma_f32_16x16x32_bf16(b0, woB[nt][0], accO[nt], 0, 0, 0);
      accO[nt] = __builtin_amdgcn_mfma_f32_16x16x32_bf16(b1, woB[nt][1], accO[nt], 0, 0, 0);
    }
#pragma unroll
    for (int nt = 0; nt < 4; ++nt) {
#pragma unroll
      for (int r = 0; r < 4; ++r) {
        const int orow = tilebase + kg * 4 + r;
        const float mk = bf2f(mask_s[orow]);
        out[outbase + (size_t)orow * NL * DCM + nt * 16 + bcol] = (accO[nt][r] + bov[nt]) * mk;
      }
    }
  }
}

extern "C" void kernel_launch(void* const* d_in, const int* in_sizes, int n_in,
                              void* d_out, int out_size, void* d_ws, size_t ws_size,
                              hipStream_t stream) {
  (void)in_sizes; (void)n_in; (void)out_size; (void)ws_size;
  const float* m   = (const float*)d_in[0];
  const float* msk = (const float*)d_in[1];
  const float* lnw = (const float*)d_in[2];
  const float* lnb = (const float*)d_in[3];
  const float* wq  = (const float*)d_in[4];
  const float* wk  = (const float*)d_in[5];
  const float* wv  = (const float*)d_in[6];
  const float* wg  = (const float*)d_in[7];
  const float* bg  = (const float*)d_in[8];
  const float* wo  = (const float*)d_in[9];
  const float* bo  = (const float*)d_in[10];
  unsigned short* wt = (unsigned short*)d_ws;              // 24576 B
  float* Mg = (float*)((char*)d_ws + 24576);               // 131072 B
  float* out = (float*)d_out;

  prep<<<dim3(128), dim3(256), 0, stream>>>(wg, wo, wv, wq, wk, wt, Mg);
  fused<<<dim3(NB * NL), dim3(256), 0, stream>>>(
      m, msk, lnw, lnb, wt, Mg, bg, bo, out);
}